// Round 16
// baseline (162.581 us; speedup 1.0000x reference)
//
#include <hip/hip_runtime.h>
#include <hip/hip_bf16.h>

#define L 4096
#define DM 128
#define NH 8
#define HD 16
#define NBH 16
#define SK 41
#define NC 192
#define NSPLIT 8
#define SLICE (L/NSPLIT)     // 512
#define KK (SLICE/16)        // 32
// 0.25 * log2(e): folds the 1/sqrt(D) scale AND the exp->exp2 conversion into Q
#define QSCALE 0.36067376022224085f

typedef __attribute__((ext_vector_type(8))) short s16x8;
typedef __attribute__((ext_vector_type(4))) float f32x4;

#define MFMA16(A,B,C) __builtin_amdgcn_mfma_f32_16x16x32_bf16(A,B,C,0,0,0)

__device__ __forceinline__ float bf2f(unsigned short h){ return __uint_as_float(((unsigned)h)<<16); }
__device__ __forceinline__ unsigned short f2bf(float f){
  unsigned u = __float_as_uint(f);
  u += 0x7FFFu + ((u>>16)&1u);
  return (unsigned short)(u>>16);
}
__device__ __forceinline__ float fast_exp2(float x){
  float r;
  asm("v_exp_f32 %0, %1" : "=v"(r) : "v"(x));
  return r;
}
// Schraudolph-style bit-trick exp2 (~±3% rel err) — ranking only, never for final values.
__device__ __forceinline__ float approx_exp2(float x){
  x = fmaxf(x, -120.f);
  const float y = fmaf(x, 8388608.f, 1064986823.f);   // x*2^23 + (127*2^23 - 366393)
  return __int_as_float((int)y);
}

// ---------------- K0: prep — split x to bf16 hi/lo; pack W's into MFMA frag layout ----------------
__global__ __launch_bounds__(256) void prep(
    const float* __restrict__ x,
    const float* __restrict__ Wq, const float* __restrict__ Wk,
    const float* __restrict__ Wv, const float* __restrict__ Wo,
    unsigned short* __restrict__ Xh, unsigned short* __restrict__ Xl,
    unsigned short* __restrict__ Wph, unsigned short* __restrict__ Wpl)
{
  const int t = threadIdx.x;
  const int blk = blockIdx.x;
  if (blk < 1024){
    const long base = (long)blk*1024 + t*4;
    float4 v = *(const float4*)(x + base);
    unsigned short h[4], lo[4];
    h[0]=f2bf(v.x); lo[0]=f2bf(v.x - bf2f(h[0]));
    h[1]=f2bf(v.y); lo[1]=f2bf(v.y - bf2f(h[1]));
    h[2]=f2bf(v.z); lo[2]=f2bf(v.z - bf2f(h[2]));
    h[3]=f2bf(v.w); lo[3]=f2bf(v.w - bf2f(h[3]));
    *(uint2*)(Xh+base) = *(uint2*)h;
    *(uint2*)(Xl+base) = *(uint2*)lo;
  } else {
    const int e = (blk-1024)*256 + t;   // 0..65535
    const int p = e >> 14;
    const int idx = e & 16383;
    const int j = idx & 7;
    const int f = idx >> 3;
    const int n = f & 127;
    const int kcg = f >> 7;             // 0..15
    const int k = (kcg>>1)*16 + (kcg&1)*8 + j;
    const float* W = (p==0)?Wq:((p==1)?Wk:((p==2)?Wv:Wo));
    const float v = W[k*128 + n];
    const unsigned short h = f2bf(v);
    Wph[e] = h;
    Wpl[e] = f2bf(v - bf2f(h));
  }
}

// ---------------- K1: MFMA QKV projection (Q pre-scaled by QSCALE) ----------------
__global__ __launch_bounds__(256) void proj_mfma(
    const unsigned short* __restrict__ Xh, const unsigned short* __restrict__ Xl,
    const unsigned short* __restrict__ Wph, const unsigned short* __restrict__ Wpl,
    const float* __restrict__ bq, const float* __restrict__ bk, const float* __restrict__ bv,
    unsigned short* __restrict__ Qh, unsigned short* __restrict__ Ql,
    unsigned short* __restrict__ Kh, unsigned short* __restrict__ Kl,
    float* __restrict__ Vo)
{
  const int p = blockIdx.y;
  const float* __restrict__ bias = (p==0)?bq:((p==1)?bk:bv);
  __shared__ __align__(16) unsigned short wh[16384];
  __shared__ __align__(16) unsigned short wl[16384];
  const int t = threadIdx.x;
  {
    const uint4* gh = (const uint4*)(Wph + (long)p*16384);
    const uint4* gl = (const uint4*)(Wpl + (long)p*16384);
    uint4* sh = (uint4*)wh; uint4* sl = (uint4*)wl;
#pragma unroll
    for (int i=0;i<8;++i){ sh[t + i*256] = gh[t + i*256]; sl[t + i*256] = gl[t + i*256]; }
  }
  __syncthreads();
  const int w = t>>6, l = t&63;
  const int lc = l&15, g = l>>4;
  const int mbase = blockIdx.x*64 + w*16;
  f32x4 acc[8];
#pragma unroll
  for (int nt=0;nt<8;++nt){ acc[nt][0]=0.f; acc[nt][1]=0.f; acc[nt][2]=0.f; acc[nt][3]=0.f; }
  const unsigned short* __restrict__ Asrc = (g<2)? Xh : Xl;
  const int koff = (g&1)*8;
  for (int kc=0; kc<8; ++kc){
    s16x8 a = *(const s16x8*)(Asrc + ((long)(mbase + lc))*128 + kc*16 + koff);
#pragma unroll
    for (int nt=0;nt<8;++nt){
      const int fi = (kc*2+(g&1))*128 + nt*16 + lc;
      s16x8 b1 = ((const s16x8*)wh)[fi];
      s16x8 b2 = ((const s16x8*)wl)[fi];
      acc[nt] = MFMA16(a, b1, acc[nt]);
      acc[nt] = MFMA16(a, b2, acc[nt]);
    }
  }
#pragma unroll
  for (int nt=0;nt<8;++nt){
    const float bb = bias[nt*16 + lc];
#pragma unroll
    for (int r=0;r<4;++r){
      const int row = mbase + g*4 + r;
      float v = acc[nt][r] + bb;
      const int b = row>>12, li = row&4095;
      const long o = (((long)(b*NH + nt))*L + li)*HD + lc;
      if (p==2){
        Vo[o] = v;
      } else {
        if (p==0) v *= QSCALE;
        const unsigned short h = f2bf(v);
        const unsigned short lo2 = f2bf(v - bf2f(h));
        if (p==0){ Qh[o]=h; Ql[o]=lo2; } else { Kh[o]=h; Kl[o]=lo2; }
      }
    }
  }
}

// ---------------- K2: partial row-max (exp2 domain), LDS-staged B, software-pipelined ----------------
__global__ __launch_bounds__(256) void rowmax_k(
    const unsigned short* __restrict__ Qh, const unsigned short* __restrict__ Ql,
    const unsigned short* __restrict__ Kh, const unsigned short* __restrict__ Kl,
    float* __restrict__ mpart)
{
  const int bh = blockIdx.y, qt = blockIdx.x, ks = blockIdx.z;
  const int t = threadIdx.x, w = t>>6, l = t&63;
  const int half = (l>>4)&1, part = l>>5, lc = l&15;
  __shared__ __align__(16) unsigned short khs[SLICE*HD];   // 16KB
  __shared__ __align__(16) unsigned short kls[SLICE*HD];   // 16KB
  {
    const uint4* gh = (const uint4*)(Kh + ((long)bh*L + ks*SLICE)*HD);
    const uint4* gl = (const uint4*)(Kl + ((long)bh*L + ks*SLICE)*HD);
    uint4* sh = (uint4*)khs; uint4* sl = (uint4*)kls;
#pragma unroll
    for (int i=0;i<4;++i){ sh[t + i*256] = gh[t + i*256]; sl[t + i*256] = gl[t + i*256]; }
  }
  s16x8 aq[4];
  {
    const unsigned short* Qsrc = part ? Ql : Qh;
#pragma unroll
    for (int m=0;m<4;++m){
      const int row = qt*256 + w*64 + m*16 + lc;
      aq[m] = *(const s16x8*)(Qsrc + (((long)bh*L + row)*HD) + half*8);
    }
  }
  __syncthreads();
  f32x4 fz; fz[0]=0.f; fz[1]=0.f; fz[2]=0.f; fz[3]=0.f;
  f32x4 rmax[4];
#pragma unroll
  for (int m=0;m<4;++m){ rmax[m][0]=rmax[m][1]=rmax[m][2]=rmax[m][3]=-3.4e38f; }
  const int boff = lc*HD + half*8;
  f32x4 accA[4], accB[4];
  {
    s16x8 b1 = *(const s16x8*)(khs + boff);
    s16x8 b2 = *(const s16x8*)(kls + boff);
#pragma unroll
    for (int m=0;m<4;++m){ accA[m] = MFMA16(aq[m], b2, fz); accA[m] = MFMA16(aq[m], b1, accA[m]); }
  }
  for (int kk=0; kk<KK-2; kk+=2){
    {
      s16x8 b1 = *(const s16x8*)(khs + (kk+1)*256 + boff);
      s16x8 b2 = *(const s16x8*)(kls + (kk+1)*256 + boff);
#pragma unroll
      for (int m=0;m<4;++m){ accB[m] = MFMA16(aq[m], b2, fz); accB[m] = MFMA16(aq[m], b1, accB[m]); }
    }
#pragma unroll
    for (int m=0;m<4;++m)
#pragma unroll
      for (int r=0;r<4;++r) rmax[m][r] = fmaxf(rmax[m][r], accA[m][r]);
    {
      s16x8 b1 = *(const s16x8*)(khs + (kk+2)*256 + boff);
      s16x8 b2 = *(const s16x8*)(kls + (kk+2)*256 + boff);
#pragma unroll
      for (int m=0;m<4;++m){ accA[m] = MFMA16(aq[m], b2, fz); accA[m] = MFMA16(aq[m], b1, accA[m]); }
    }
#pragma unroll
    for (int m=0;m<4;++m)
#pragma unroll
      for (int r=0;r<4;++r) rmax[m][r] = fmaxf(rmax[m][r], accB[m][r]);
  }
  {
    s16x8 b1 = *(const s16x8*)(khs + (KK-1)*256 + boff);
    s16x8 b2 = *(const s16x8*)(kls + (KK-1)*256 + boff);
#pragma unroll
    for (int m=0;m<4;++m){ accB[m] = MFMA16(aq[m], b2, fz); accB[m] = MFMA16(aq[m], b1, accB[m]); }
  }
#pragma unroll
  for (int m=0;m<4;++m)
#pragma unroll
    for (int r=0;r<4;++r) rmax[m][r] = fmaxf(fmaxf(rmax[m][r], accA[m][r]), accB[m][r]);
#pragma unroll
  for (int m=0;m<4;++m){
#pragma unroll
    for (int r=0;r<4;++r){
      float v = rmax[m][r];
      v = fmaxf(v, __shfl_xor(v, 1));
      v = fmaxf(v, __shfl_xor(v, 2));
      v = fmaxf(v, __shfl_xor(v, 4));
      v = fmaxf(v, __shfl_xor(v, 8));
      rmax[m][r] = v;
    }
  }
  if (lc == 0){
    const int q4 = l>>4;
#pragma unroll
    for (int m=0;m<4;++m){
#pragma unroll
      for (int r=0;r<4;++r){
        const int row = qt*256 + w*64 + m*16 + q4*4 + r;
        mpart[((long)ks*NBH + bh)*L + row] = rmax[m][r];
      }
    }
  }
}

// ---------------- K3: APPROX partial column sums (Schraudolph exp2, ranking only) ----------------
__global__ __launch_bounds__(256) void colexp_k(
    const unsigned short* __restrict__ Kh, const unsigned short* __restrict__ Kl,
    const unsigned short* __restrict__ Qh, const unsigned short* __restrict__ Ql,
    const float* __restrict__ mpart, float* __restrict__ cspart)
{
  const int bh = blockIdx.y, kt = blockIdx.x, qs = blockIdx.z;
  const int t = threadIdx.x, w = t>>6, l = t&63;
  const int half = (l>>4)&1, part = l>>5, lc = l&15;
  __shared__ __align__(16) unsigned short qhs[SLICE*HD];   // 16KB
  __shared__ __align__(16) unsigned short qls[SLICE*HD];   // 16KB
  __shared__ float ws_s[SLICE];                            // 2KB
  {
    const uint4* gh = (const uint4*)(Qh + ((long)bh*L + qs*SLICE)*HD);
    const uint4* gl = (const uint4*)(Ql + ((long)bh*L + qs*SLICE)*HD);
    uint4* sh = (uint4*)qhs; uint4* sl = (uint4*)qls;
#pragma unroll
    for (int i=0;i<4;++i){ sh[t + i*256] = gh[t + i*256]; sl[t + i*256] = gl[t + i*256]; }
#pragma unroll
    for (int rr=0; rr<2; ++rr){
      const int tq = t + rr*256;
      const long qi = (long)bh*L + qs*SLICE + tq;
      float m = -3.4e38f;
#pragma unroll
      for (int p=0;p<NSPLIT;++p) m = fmaxf(m, mpart[(long)p*NBH*L + qi]);
      ws_s[tq] = fast_exp2(-m);
    }
  }
  s16x8 ak[4];
  {
    const unsigned short* Ksrc = part ? Kl : Kh;
#pragma unroll
    for (int m=0;m<4;++m){
      const int key = kt*256 + w*64 + m*16 + lc;
      ak[m] = *(const s16x8*)(Ksrc + (((long)bh*L + key)*HD) + half*8);
    }
  }
  __syncthreads();
  f32x4 fz; fz[0]=0.f; fz[1]=0.f; fz[2]=0.f; fz[3]=0.f;
  f32x4 csum[4];
#pragma unroll
  for (int m=0;m<4;++m){ csum[m][0]=0.f; csum[m][1]=0.f; csum[m][2]=0.f; csum[m][3]=0.f; }
  const int boff = lc*HD + half*8;
  f32x4 accA[4], accB[4];
  {
    s16x8 b1 = *(const s16x8*)(qhs + boff);
    s16x8 b2 = *(const s16x8*)(qls + boff);
#pragma unroll
    for (int m=0;m<4;++m){ accA[m] = MFMA16(ak[m], b2, fz); accA[m] = MFMA16(ak[m], b1, accA[m]); }
  }
  for (int kk=0; kk<KK-2; kk+=2){
    {
      s16x8 b1 = *(const s16x8*)(qhs + (kk+1)*256 + boff);
      s16x8 b2 = *(const s16x8*)(qls + (kk+1)*256 + boff);
#pragma unroll
      for (int m=0;m<4;++m){ accB[m] = MFMA16(ak[m], b2, fz); accB[m] = MFMA16(ak[m], b1, accB[m]); }
    }
    {
      const float cw = ws_s[kk*16 + lc];
#pragma unroll
      for (int m=0;m<4;++m)
#pragma unroll
        for (int r=0;r<4;++r)
          csum[m][r] = fmaf(approx_exp2(accA[m][r]), cw, csum[m][r]);
    }
    {
      s16x8 b1 = *(const s16x8*)(qhs + (kk+2)*256 + boff);
      s16x8 b2 = *(const s16x8*)(qls + (kk+2)*256 + boff);
#pragma unroll
      for (int m=0;m<4;++m){ accA[m] = MFMA16(ak[m], b2, fz); accA[m] = MFMA16(ak[m], b1, accA[m]); }
    }
    {
      const float cw = ws_s[(kk+1)*16 + lc];
#pragma unroll
      for (int m=0;m<4;++m)
#pragma unroll
        for (int r=0;r<4;++r)
          csum[m][r] = fmaf(approx_exp2(accB[m][r]), cw, csum[m][r]);
    }
  }
  {
    s16x8 b1 = *(const s16x8*)(qhs + (KK-1)*256 + boff);
    s16x8 b2 = *(const s16x8*)(qls + (KK-1)*256 + boff);
#pragma unroll
    for (int m=0;m<4;++m){ accB[m] = MFMA16(ak[m], b2, fz); accB[m] = MFMA16(ak[m], b1, accB[m]); }
  }
  {
    const float cwA = ws_s[(KK-2)*16 + lc];
    const float cwB = ws_s[(KK-1)*16 + lc];
#pragma unroll
    for (int m=0;m<4;++m)
#pragma unroll
      for (int r=0;r<4;++r){
        csum[m][r] = fmaf(approx_exp2(accA[m][r]), cwA, csum[m][r]);
        csum[m][r] = fmaf(approx_exp2(accB[m][r]), cwB, csum[m][r]);
      }
  }
#pragma unroll
  for (int m=0;m<4;++m){
#pragma unroll
    for (int r=0;r<4;++r){
      float v = csum[m][r];
      v += __shfl_xor(v, 1);
      v += __shfl_xor(v, 2);
      v += __shfl_xor(v, 4);
      v += __shfl_xor(v, 8);
      csum[m][r] = v;
    }
  }
  if (lc == 0){
    const int k4 = l>>4;
#pragma unroll
    for (int m=0;m<4;++m){
#pragma unroll
      for (int r=0;r<4;++r){
        const int key = kt*256 + w*64 + m*16 + k4*4 + r;
        cspart[((long)qs*NBH + bh)*L + key] = csum[m][r];
      }
    }
  }
}

// ---------------- K4: radix-select top-192 CANDIDATES by approx sums; gather cand K-frags ----------------
__global__ __launch_bounds__(256) void topk_cand(
    const float* __restrict__ cspart,
    const unsigned short* __restrict__ Kh, const unsigned short* __restrict__ Kl,
    int* __restrict__ candIdx,
    unsigned short* __restrict__ Kch, unsigned short* __restrict__ Kcl)
{
  const int bh = blockIdx.x;
  const int t = threadIdx.x;
  __shared__ float vals[4096];
  __shared__ unsigned hist[2048];
  __shared__ unsigned suf[256];
  __shared__ int meta[4];
  __shared__ int sel[NC];
  __shared__ int tiei[4096];

  for (int i=t; i<1024; i+=256){
    float4 s = {0.f,0.f,0.f,0.f};
#pragma unroll
    for (int p=0;p<NSPLIT;++p){
      float4 v = *(const float4*)(cspart + ((long)p*NBH + bh)*L + i*4);
      s.x += v.x; s.y += v.y; s.z += v.z; s.w += v.w;
    }
    *(float4*)&vals[i*4] = s;
  }
  __syncthreads();

  int target = NC;
  unsigned B1 = 0, P2 = 0, T = 0;
#pragma unroll
  for (int pass=0; pass<3; ++pass){
    const int nb = (pass<2) ? 2048 : 1024;
    const int chunk = nb >> 8;
    for (int i=t;i<nb;i+=256) hist[i]=0u;
    __syncthreads();
    for (int i=t;i<4096;i+=256){
      const unsigned u = __float_as_uint(vals[i]);
      bool ok; int bk;
      if (pass==0){ ok = true;              bk = (int)(u>>21); }
      else if (pass==1){ ok = ((u>>21)==B1); bk = (int)((u>>10)&0x7FFu); }
      else { ok = ((u>>10)==P2);            bk = (int)(u&0x3FFu); }
      if (ok) atomicAdd(&hist[bk], 1u);
    }
    __syncthreads();
    {
      unsigned c=0;
#pragma unroll
      for (int b=0;b<8;++b) if (b<chunk) c += hist[t*chunk+b];
      suf[t]=c;
    }
    __syncthreads();
    for (int off=1; off<256; off<<=1){
      unsigned add = (t+off<256)? suf[t+off] : 0u;
      __syncthreads();
      suf[t] += add;
      __syncthreads();
    }
    {
      const unsigned mysuf = suf[t];
      const unsigned nxt = (t==255)?0u:suf[t+1];
      if (mysuf >= (unsigned)target && nxt < (unsigned)target){
        unsigned running = nxt;
        for (int b=t*chunk+chunk-1; b>=t*chunk; --b){
          const unsigned h = hist[b];
          if (running + h >= (unsigned)target){ meta[0]=b; meta[1]=(int)running; break; }
          running += h;
        }
      }
    }
    __syncthreads();
    const unsigned B = (unsigned)meta[0];
    target -= meta[1];
    if (pass==0) B1 = B;
    else if (pass==1) P2 = (B1<<11)|B;
    else T = (P2<<10)|B;
    __syncthreads();
  }
  if (t==0){ meta[2]=0; meta[3]=0; }
  __syncthreads();
  for (int i=t;i<4096;i+=256){
    const unsigned u = __float_as_uint(vals[i]);
    if (u > T){ int p = atomicAdd(&meta[2],1); sel[p]=i; }
    else if (u == T){ int p = atomicAdd(&meta[3],1); tiei[p]=i; }
  }
  __syncthreads();
  const int ngt = meta[2];
  const int ntie = meta[3];
  for (int j=t; j<ntie; j+=256){
    const int x = tiei[j];
    int rk=0;
    for (int k=0;k<ntie;++k) rk += (tiei[k] < x);
    if (rk < target) sel[ngt+rk] = x;
  }
  __syncthreads();
  if (t < NC) candIdx[bh*NC + t] = sel[t];
  for (int i=t; i<NC*HD; i+=256){
    const int j=i>>4, dd=i&15;
    const int key=sel[j];
    const long src=((long)bh*L+key)*HD+dd;
    const long dst=((long)bh*NC+j)*HD+dd;
    Kch[dst]=Kh[src];
    Kcl[dst]=Kl[src];
  }
}

// ---------------- K4b: EXACT column sums for the 192 candidates ----------------
// grid (8 qs, 16 bh), block 256 = 4 waves; wave handles 48 cands (3 tiles).
__global__ __launch_bounds__(256) void colexp_exact(
    const unsigned short* __restrict__ Kch, const unsigned short* __restrict__ Kcl,
    const unsigned short* __restrict__ Qh, const unsigned short* __restrict__ Ql,
    const float* __restrict__ mpart, float* __restrict__ cse)
{
  const int qs = blockIdx.x, bh = blockIdx.y;
  const int t = threadIdx.x, w = t>>6, l = t&63;
  const int half = (l>>4)&1, part = l>>5, lc = l&15;
  __shared__ __align__(16) unsigned short qhs[SLICE*HD];
  __shared__ __align__(16) unsigned short qls[SLICE*HD];
  __shared__ float ws_s[SLICE];
  {
    const uint4* gh = (const uint4*)(Qh + ((long)bh*L + qs*SLICE)*HD);
    const uint4* gl = (const uint4*)(Ql + ((long)bh*L + qs*SLICE)*HD);
    uint4* sh = (uint4*)qhs; uint4* sl = (uint4*)qls;
#pragma unroll
    for (int i=0;i<4;++i){ sh[t + i*256] = gh[t + i*256]; sl[t + i*256] = gl[t + i*256]; }
#pragma unroll
    for (int rr=0; rr<2; ++rr){
      const int tq = t + rr*256;
      const long qi = (long)bh*L + qs*SLICE + tq;
      float m = -3.4e38f;
#pragma unroll
      for (int p=0;p<NSPLIT;++p) m = fmaxf(m, mpart[(long)p*NBH*L + qi]);
      ws_s[tq] = fast_exp2(-m);
    }
  }
  s16x8 ak[3];
  {
    const unsigned short* Ksrc = part ? Kcl : Kch;
#pragma unroll
    for (int m=0;m<3;++m){
      const int row = w*48 + m*16 + lc;
      ak[m] = *(const s16x8*)(Ksrc + ((long)bh*NC + row)*HD + half*8);
    }
  }
  __syncthreads();
  f32x4 fz; fz[0]=0.f; fz[1]=0.f; fz[2]=0.f; fz[3]=0.f;
  f32x4 csum[3];
#pragma unroll
  for (int m=0;m<3;++m){ csum[m][0]=0.f; csum[m][1]=0.f; csum[m][2]=0.f; csum[m][3]=0.f; }
  const int boff = lc*HD + half*8;
  for (int kk=0; kk<KK; ++kk){
    s16x8 b1 = *(const s16x8*)(qhs + kk*256 + boff);
    s16x8 b2 = *(const s16x8*)(qls + kk*256 + boff);
    const float cw = ws_s[kk*16 + lc];
#pragma unroll
    for (int m=0;m<3;++m){
      f32x4 acc = MFMA16(ak[m], b2, fz);
      acc = MFMA16(ak[m], b1, acc);
#pragma unroll
      for (int r=0;r<4;++r)
        csum[m][r] = fmaf(fast_exp2(acc[r]), cw, csum[m][r]);
    }
  }
#pragma unroll
  for (int m=0;m<3;++m){
#pragma unroll
    for (int r=0;r<4;++r){
      float v = csum[m][r];
      v += __shfl_xor(v, 1);
      v += __shfl_xor(v, 2);
      v += __shfl_xor(v, 4);
      v += __shfl_xor(v, 8);
      csum[m][r] = v;
    }
  }
  if (lc == 0){
    const int k4 = l>>4;
#pragma unroll
    for (int m=0;m<3;++m){
#pragma unroll
      for (int r=0;r<4;++r){
        const int c = w*48 + m*16 + k4*4 + r;
        cse[((long)qs*NBH + bh)*NC + c] = csum[m][r];
      }
    }
  }
}

// ---------------- K4c: final exact top-41 among candidates + gather Ks/Vs ----------------
__global__ __launch_bounds__(256) void topk_final(
    const float* __restrict__ cse, const int* __restrict__ candIdx,
    const unsigned short* __restrict__ Kh, const unsigned short* __restrict__ Kl,
    const float* __restrict__ V,
    float* __restrict__ Ks, float* __restrict__ Vs)
{
  const int bh = blockIdx.x;
  const int t = threadIdx.x;
  __shared__ float v[NC];
  __shared__ int idx[NC];
  __shared__ unsigned char fl[NC];
  __shared__ int sorted[SK];
  if (t < NC){
    float s = 0.f;
#pragma unroll
    for (int p=0;p<NSPLIT;++p) s += cse[((long)p*NBH + bh)*NC + t];
    v[t] = s;
    idx[t] = candIdx[bh*NC + t];
  }
  __syncthreads();
  if (t < NC){
    const float mv = v[t]; const int mi = idx[t];
    int rank = 0;
    for (int j=0;j<NC;++j)
      rank += (v[j] > mv) || (v[j] == mv && idx[j] < mi);
    fl[t] = (rank < SK) ? 1 : 0;
  }
  __syncthreads();
  if (t < NC && fl[t]){
    const int mi = idx[t];
    int pos = 0;
    for (int j=0;j<NC;++j) pos += (fl[j] && idx[j] < mi);
    sorted[pos] = mi;
  }
  __syncthreads();
  for (int i=t;i<SK*HD;i+=256){
    const int j=i>>4, dd=i&15;
    const int key=sorted[j];
    const long src=((long)bh*L+key)*HD+dd;
    Ks[(long)bh*SK*HD+i]=bf2f(Kh[src])+bf2f(Kl[src]);
    Vs[(long)bh*SK*HD+i]=V[src];
  }
}

// ---------------- K5: sampled attention — lane-pair split, 2-pass register softmax ----------------
__global__ __launch_bounds__(256) void sattn(
    const unsigned short* __restrict__ Qh, const unsigned short* __restrict__ Ql,
    const float* __restrict__ Ks, const float* __restrict__ Vs,
    unsigned short* __restrict__ AOh, unsigned short* __restrict__ AOl)
{
  const int bh = blockIdx.y, qb = blockIdx.x;
  const int t = threadIdx.x;
  __shared__ float ks[SK*HD], vs[SK*HD];
  for (int i=t; i<SK*HD; i+=256){
    ks[i] = Ks[(long)bh*SK*HD + i];
    vs[i] = Vs[(long)bh*SK*HD + i];
  }
  __syncthreads();
  const int q = qb*128 + (t>>1);
  const int half = t&1;
  const long qo = ((long)bh*L + q)*HD;
  float qv[16];
  {
    s16x8 h0 = *(const s16x8*)(Qh+qo);
    s16x8 h1 = *(const s16x8*)(Qh+qo+8);
    s16x8 l0 = *(const s16x8*)(Ql+qo);
    s16x8 l1 = *(const s16x8*)(Ql+qo+8);
#pragma unroll
    for (int d=0; d<8; ++d){
      qv[d]   = bf2f((unsigned short)h0[d]) + bf2f((unsigned short)l0[d]);
      qv[d+8] = bf2f((unsigned short)h1[d]) + bf2f((unsigned short)l1[d]);
    }
  }
  float sc[21];
#pragma unroll
  for (int i=0;i<21;++i){
    const int j = half + 2*i;
    if (j < SK){
      float4 k0 = *(const float4*)&ks[j*HD+0];
      float4 k1 = *(const float4*)&ks[j*HD+4];
      float4 k2 = *(const float4*)&ks[j*HD+8];
      float4 k3 = *(const float4*)&ks[j*HD+12];
      float s = qv[0]*k0.x;
      s = fmaf(qv[1],k0.y,s); s = fmaf(qv[2],k0.z,s); s = fmaf(qv[3],k0.w,s);
      s = fmaf(qv[4],k1.x,s); s = fmaf(qv[5],k1.y,s); s = fmaf(qv[6],k1.z,s); s = fmaf(qv[7],k1.w,s);
      s = fmaf(qv[8],k2.x,s); s = fmaf(qv[9],k2.y,s); s = fmaf(qv[10],k2.z,s); s = fmaf(qv[11],k2.w,s);
      s = fmaf(qv[12],k3.x,s); s = fmaf(qv[13],k3.y,s); s = fmaf(qv[14],k3.z,s); s = fmaf(qv[15],k3.w,s);
      sc[i] = s;
    } else {
      sc[i] = -3.4e38f;
    }
  }
  float m = sc[0];
#pragma unroll
  for (int i=1;i<21;++i) m = fmaxf(m, sc[i]);
  float lrun = 0.f, out[16];
#pragma unroll
  for (int d=0; d<16; ++d) out[d] = 0.f;
#pragma unroll
  for (int i=0;i<21;++i){
    const int j = half + 2*i;
    const float p = fast_exp2(sc[i] - m);
    lrun += p;
    if (j < SK){
      float4 v0 = *(const float4*)&vs[j*HD+0];
      float4 v1 = *(const float4*)&vs[j*HD+4];
      float4 v2 = *(const float4*)&vs[j*HD+8];
      float4 v3 = *(const float4*)&vs[j*HD+12];
      out[0]=fmaf(p,v0.x,out[0]); out[1]=fmaf(p,v0.y,out[1]); out[2]=fmaf(p,v0.z,out[2]); out[3]=fmaf(p,v0.w,out[3]);
      out[4]=fmaf(p,v1.x,out[4]); out[5]=fmaf(p,v1.y,out[5]); out[6]=fmaf(p,v1.z,out[6]); out[7]=fmaf(p,v1.w,out[7]);
      out[8]=fmaf(p,v2.x,out[8]); out[9]=fmaf(p,v2.y,out[9]); out[10]=fmaf(p,v2.z,out[10]); out[11]=fmaf(p,v2.w,out[11]);
      out[12]=fmaf(p,v3.x,out[12]); out[13]=fmaf(p,v3.y,out[13]); out[14]=fmaf(p,v3.z,out[14]); out[15]=fmaf(p,v3.w,out[15]);
    }
  }
  const float mo = __shfl_xor(m, 1);
  const float lo = __shfl_xor(lrun, 1);
  const float mm = fmaxf(m, mo);
  const float cs_ = fast_exp2(m - mm);
  const float co_ = fast_exp2(mo - mm);
  const float ltot = fmaf(lrun, cs_, lo*co_);
  const float inv = 1.f / ltot;
#pragma unroll
  for (int d=0; d<16; ++d){
    const float ov = __shfl_xor(out[d], 1);
    out[d] = fmaf(out[d]*cs_, inv, ov*co_*inv);
  }
  if (half == 0){
    const int b = bh>>3, h = bh&7;
    const long row = (long)b*L + q;
    unsigned short hv[16], lv[16];
#pragma unroll
    for (int d=0; d<16; ++d){
      const float v = out[d];
      hv[d] = f2bf(v);
      lv[d] = f2bf(v - bf2f(hv[d]));
    }
    unsigned short* oh = AOh + row*DM + h*HD;
    unsigned short* ol = AOl + row*DM + h*HD;
    *(uint4*)(oh)   = *(uint4*)(hv);
    *(uint4*)(oh+8) = *(uint4*)(hv+8);
    *(uint4*)(ol)   = *(uint4*)(lv);
    *(uint4*)(ol+8) = *(uint4*)(lv+8);
  }
}

// ---------------- K6: MFMA output projection ----------------
__global__ __launch_bounds__(256) void outproj_mfma(
    const unsigned short* __restrict__ AOh, const unsigned short* __restrict__ AOl,
    const unsigned short* __restrict__ Wph, const unsigned short* __restrict__ Wpl,
    const float* __restrict__ bo, float* __restrict__ out)
{
  __shared__ __align__(16) unsigned short wh[16384];
  __shared__ __align__(16) unsigned short wl[16384];
  const int t = threadIdx.x;
  {
    const uint4* gh = (const uint4*)(Wph + (long)3*16384);
    const uint4* gl = (const uint4*)(Wpl + (long)3*16384);
    uint4* sh = (uint4*)wh; uint4* sl = (uint4*)wl;
#pragma unroll
    for (int i=0;i<8;++i){ sh[t + i*256] = gh[t + i*256]; sl[t + i*256] = gl[t + i*256]; }
  }
  __syncthreads();
  const int w = t>>6, l = t&63;
  const int lc = l&15, g = l>>4;
  const int mbase = blockIdx.x*64 + w*16;
  f32x4 acc[8];
#pragma unroll
  for (int nt=0;nt<8;++nt){ acc[nt][0]=0.f; acc[nt][1]=0.f; acc[nt][2]=0.f; acc[nt][3]=0.f; }
  const unsigned short* __restrict__ Asrc = (g<2)? AOh : AOl;
  const int koff = (g&1)*8;
  for (int kc=0; kc<8; ++kc){
    s16x8 a = *(const s16x8*)(Asrc + ((long)(mbase + lc))*128 + kc*16 + koff);
#pragma unroll
    for (int nt=0;nt<8;++nt){
      const int fi = (kc*2+(g&1))*128 + nt*16 + lc;
      s16x8 b1 = ((const s16x8*)wh)[fi];
      s16x8 b2 = ((const s16x8*)wl)[fi];
      acc[nt] = MFMA16(a, b1, acc[nt]);
      acc[nt] = MFMA16(a, b2, acc[nt]);
    }
  }
#pragma unroll
  for (int nt=0;nt<8;++nt){
    const float bb = bo[nt*16 + lc];
#pragma unroll
    for (int r=0;r<4;++r){
      const int row = mbase + g*4 + r;
      out[(long)row*DM + nt*16 + lc] = acc[nt][r] + bb;
    }
  }
}

extern "C" void kernel_launch(void* const* d_in, const int* in_sizes, int n_in,
                              void* d_out, int out_size, void* d_ws, size_t ws_size,
                              hipStream_t stream)
{
  const float* x  = (const float*)d_in[0];
  const float* Wq = (const float*)d_in[1];
  const float* bq = (const float*)d_in[2];
  const float* Wk = (const float*)d_in[3];
  const float* bk = (const float*)d_in[4];
  const float* Wv = (const float*)d_in[5];
  const float* bv = (const float*)d_in[6];
  const float* Wo = (const float*)d_in[7];
  const float* bo = (const float*)d_in[8];
  float* out = (float*)d_out;

  char* wsp = (char*)d_ws;
  size_t o = 0;
  auto alloc = [&](size_t bytes)->char*{
    char* p = wsp + o; o += (bytes + 255) & ~(size_t)255; return p;
  };
  unsigned short* Qh = (unsigned short*)alloc((size_t)NBH*L*HD*2);
  unsigned short* Ql = (unsigned short*)alloc((size_t)NBH*L*HD*2);
  unsigned short* Kh = (unsigned short*)alloc((size_t)NBH*L*HD*2);
  unsigned short* Kl = (unsigned short*)alloc((size_t)NBH*L*HD*2);
  float* Vv    = (float*)alloc((size_t)NBH*L*HD*4);
  float* mpart = (float*)alloc((size_t)NSPLIT*NBH*L*4);
  float* cspart= (float*)alloc((size_t)NSPLIT*NBH*L*4);
  int*   candI = (int*)alloc((size_t)NBH*NC*4);
  unsigned short* Kch = (unsigned short*)alloc((size_t)NBH*NC*HD*2);
  unsigned short* Kcl = (unsigned short*)alloc((size_t)NBH*NC*HD*2);
  float* cse   = (float*)alloc((size_t)NSPLIT*NBH*NC*4);
  float* Ks    = (float*)alloc((size_t)NBH*SK*HD*4);
  float* Vs    = (float*)alloc((size_t)NBH*SK*HD*4);
  unsigned short* Xh  = (unsigned short*)alloc((size_t)2*L*DM*2);
  unsigned short* Xl  = (unsigned short*)alloc((size_t)2*L*DM*2);
  unsigned short* AOh = (unsigned short*)alloc((size_t)2*L*DM*2);
  unsigned short* AOl = (unsigned short*)alloc((size_t)2*L*DM*2);
  unsigned short* Wph = (unsigned short*)alloc((size_t)4*16384*2);
  unsigned short* Wpl = (unsigned short*)alloc((size_t)4*16384*2);

  prep<<<1280,256,0,stream>>>(x,Wq,Wk,Wv,Wo,Xh,Xl,Wph,Wpl);
  proj_mfma<<<dim3(128,3),256,0,stream>>>(Xh,Xl,Wph,Wpl,bq,bk,bv,Qh,Ql,Kh,Kl,Vv);
  rowmax_k<<<dim3(16,16,NSPLIT),256,0,stream>>>(Qh,Ql,Kh,Kl,mpart);
  colexp_k<<<dim3(16,16,NSPLIT),256,0,stream>>>(Kh,Kl,Qh,Ql,mpart,cspart);
  topk_cand<<<16,256,0,stream>>>(cspart,Kh,Kl,candI,Kch,Kcl);
  colexp_exact<<<dim3(8,16),256,0,stream>>>(Kch,Kcl,Qh,Ql,mpart,cse);
  topk_final<<<16,256,0,stream>>>(cse,candI,Kh,Kl,Vv,Ks,Vs);
  sattn<<<dim3(32,16),256,0,stream>>>(Qh,Ql,Ks,Vs,AOh,AOl);
  outproj_mfma<<<128,256,0,stream>>>(AOh,AOl,Wph,Wpl,bo,out);
}

// Round 17
// 132.043 us; speedup vs baseline: 1.2313x; 1.2313x over previous
//
#include <hip/hip_runtime.h>
#include <hip/hip_bf16.h>

#define L 4096
#define DM 128
#define NH 8
#define HD 16
#define NBH 16
#define SK 41
#define NSPLIT 8
#define SLICE (L/NSPLIT)     // 512
#define KK (SLICE/16)        // 32
// 0.25 * log2(e): folds the 1/sqrt(D) scale AND the exp->exp2 conversion into Q
#define QSCALE 0.36067376022224085f

typedef __attribute__((ext_vector_type(8))) short s16x8;
typedef __attribute__((ext_vector_type(4))) float f32x4;

#define MFMA16(A,B,C) __builtin_amdgcn_mfma_f32_16x16x32_bf16(A,B,C,0,0,0)

__device__ __forceinline__ float bf2f(unsigned short h){ return __uint_as_float(((unsigned)h)<<16); }
__device__ __forceinline__ unsigned short f2bf(float f){
  unsigned u = __float_as_uint(f);
  u += 0x7FFFu + ((u>>16)&1u);
  return (unsigned short)(u>>16);
}
__device__ __forceinline__ float fast_exp2(float x){
  float r;
  asm("v_exp_f32 %0, %1" : "=v"(r) : "v"(x));
  return r;
}

// ---------------- K0: prep — split x to bf16 hi/lo; pack W's into MFMA frag layout ----------------
__global__ __launch_bounds__(256) void prep(
    const float* __restrict__ x,
    const float* __restrict__ Wq, const float* __restrict__ Wk,
    const float* __restrict__ Wv, const float* __restrict__ Wo,
    unsigned short* __restrict__ Xh, unsigned short* __restrict__ Xl,
    unsigned short* __restrict__ Wph, unsigned short* __restrict__ Wpl)
{
  const int t = threadIdx.x;
  const int blk = blockIdx.x;
  if (blk < 1024){
    const long base = (long)blk*1024 + t*4;
    float4 v = *(const float4*)(x + base);
    unsigned short h[4], lo[4];
    h[0]=f2bf(v.x); lo[0]=f2bf(v.x - bf2f(h[0]));
    h[1]=f2bf(v.y); lo[1]=f2bf(v.y - bf2f(h[1]));
    h[2]=f2bf(v.z); lo[2]=f2bf(v.z - bf2f(h[2]));
    h[3]=f2bf(v.w); lo[3]=f2bf(v.w - bf2f(h[3]));
    *(uint2*)(Xh+base) = *(uint2*)h;
    *(uint2*)(Xl+base) = *(uint2*)lo;
  } else {
    const int e = (blk-1024)*256 + t;   // 0..65535
    const int p = e >> 14;
    const int idx = e & 16383;
    const int j = idx & 7;
    const int f = idx >> 3;
    const int n = f & 127;
    const int kcg = f >> 7;             // 0..15
    const int k = (kcg>>1)*16 + (kcg&1)*8 + j;
    const float* W = (p==0)?Wq:((p==1)?Wk:((p==2)?Wv:Wo));
    const float v = W[k*128 + n];
    const unsigned short h = f2bf(v);
    Wph[e] = h;
    Wpl[e] = f2bf(v - bf2f(h));
  }
}

// ---------------- K1: MFMA QKV projection (Q pre-scaled by QSCALE) ----------------
// grid (128, 3), block 256 (4 waves). Wave: 16 rows x 128 cols, K=128.
__global__ __launch_bounds__(256) void proj_mfma(
    const unsigned short* __restrict__ Xh, const unsigned short* __restrict__ Xl,
    const unsigned short* __restrict__ Wph, const unsigned short* __restrict__ Wpl,
    const float* __restrict__ bq, const float* __restrict__ bk, const float* __restrict__ bv,
    unsigned short* __restrict__ Qh, unsigned short* __restrict__ Ql,
    unsigned short* __restrict__ Kh, unsigned short* __restrict__ Kl,
    float* __restrict__ Vo)
{
  const int p = blockIdx.y;
  const float* __restrict__ bias = (p==0)?bq:((p==1)?bk:bv);
  __shared__ __align__(16) unsigned short wh[16384];
  __shared__ __align__(16) unsigned short wl[16384];
  const int t = threadIdx.x;
  {
    const uint4* gh = (const uint4*)(Wph + (long)p*16384);
    const uint4* gl = (const uint4*)(Wpl + (long)p*16384);
    uint4* sh = (uint4*)wh; uint4* sl = (uint4*)wl;
#pragma unroll
    for (int i=0;i<8;++i){ sh[t + i*256] = gh[t + i*256]; sl[t + i*256] = gl[t + i*256]; }
  }
  __syncthreads();
  const int w = t>>6, l = t&63;
  const int lc = l&15, g = l>>4;
  const int mbase = blockIdx.x*64 + w*16;
  f32x4 acc[8];
#pragma unroll
  for (int nt=0;nt<8;++nt){ acc[nt][0]=0.f; acc[nt][1]=0.f; acc[nt][2]=0.f; acc[nt][3]=0.f; }
  const unsigned short* __restrict__ Asrc = (g<2)? Xh : Xl;
  const int koff = (g&1)*8;
  for (int kc=0; kc<8; ++kc){
    s16x8 a = *(const s16x8*)(Asrc + ((long)(mbase + lc))*128 + kc*16 + koff);
#pragma unroll
    for (int nt=0;nt<8;++nt){
      const int fi = (kc*2+(g&1))*128 + nt*16 + lc;
      s16x8 b1 = ((const s16x8*)wh)[fi];
      s16x8 b2 = ((const s16x8*)wl)[fi];
      acc[nt] = MFMA16(a, b1, acc[nt]);
      acc[nt] = MFMA16(a, b2, acc[nt]);
    }
  }
#pragma unroll
  for (int nt=0;nt<8;++nt){
    const float bb = bias[nt*16 + lc];
#pragma unroll
    for (int r=0;r<4;++r){
      const int row = mbase + g*4 + r;
      float v = acc[nt][r] + bb;
      const int b = row>>12, li = row&4095;
      const long o = (((long)(b*NH + nt))*L + li)*HD + lc;
      if (p==2){
        Vo[o] = v;
      } else {
        if (p==0) v *= QSCALE;
        const unsigned short h = f2bf(v);
        const unsigned short lo2 = f2bf(v - bf2f(h));
        if (p==0){ Qh[o]=h; Ql[o]=lo2; } else { Kh[o]=h; Kl[o]=lo2; }
      }
    }
  }
}

// ---------------- K2: partial row-max (exp2 domain), LDS-staged B, software-pipelined ----------------
__global__ __launch_bounds__(256) void rowmax_k(
    const unsigned short* __restrict__ Qh, const unsigned short* __restrict__ Ql,
    const unsigned short* __restrict__ Kh, const unsigned short* __restrict__ Kl,
    float* __restrict__ mpart)
{
  const int bh = blockIdx.y, qt = blockIdx.x, ks = blockIdx.z;
  const int t = threadIdx.x, w = t>>6, l = t&63;
  const int half = (l>>4)&1, part = l>>5, lc = l&15;
  __shared__ __align__(16) unsigned short khs[SLICE*HD];   // 16KB
  __shared__ __align__(16) unsigned short kls[SLICE*HD];   // 16KB
  {
    const uint4* gh = (const uint4*)(Kh + ((long)bh*L + ks*SLICE)*HD);
    const uint4* gl = (const uint4*)(Kl + ((long)bh*L + ks*SLICE)*HD);
    uint4* sh = (uint4*)khs; uint4* sl = (uint4*)kls;
#pragma unroll
    for (int i=0;i<4;++i){ sh[t + i*256] = gh[t + i*256]; sl[t + i*256] = gl[t + i*256]; }
  }
  s16x8 aq[4];
  {
    const unsigned short* Qsrc = part ? Ql : Qh;
#pragma unroll
    for (int m=0;m<4;++m){
      const int row = qt*256 + w*64 + m*16 + lc;
      aq[m] = *(const s16x8*)(Qsrc + (((long)bh*L + row)*HD) + half*8);
    }
  }
  __syncthreads();
  f32x4 fz; fz[0]=0.f; fz[1]=0.f; fz[2]=0.f; fz[3]=0.f;
  f32x4 rmax[4];
#pragma unroll
  for (int m=0;m<4;++m){ rmax[m][0]=rmax[m][1]=rmax[m][2]=rmax[m][3]=-3.4e38f; }
  const int boff = lc*HD + half*8;
  f32x4 accA[4], accB[4];
  {
    s16x8 b1 = *(const s16x8*)(khs + boff);
    s16x8 b2 = *(const s16x8*)(kls + boff);
#pragma unroll
    for (int m=0;m<4;++m){ accA[m] = MFMA16(aq[m], b2, fz); accA[m] = MFMA16(aq[m], b1, accA[m]); }
  }
  for (int kk=0; kk<KK-2; kk+=2){
    {
      s16x8 b1 = *(const s16x8*)(khs + (kk+1)*256 + boff);
      s16x8 b2 = *(const s16x8*)(kls + (kk+1)*256 + boff);
#pragma unroll
      for (int m=0;m<4;++m){ accB[m] = MFMA16(aq[m], b2, fz); accB[m] = MFMA16(aq[m], b1, accB[m]); }
    }
#pragma unroll
    for (int m=0;m<4;++m)
#pragma unroll
      for (int r=0;r<4;++r) rmax[m][r] = fmaxf(rmax[m][r], accA[m][r]);
    {
      s16x8 b1 = *(const s16x8*)(khs + (kk+2)*256 + boff);
      s16x8 b2 = *(const s16x8*)(kls + (kk+2)*256 + boff);
#pragma unroll
      for (int m=0;m<4;++m){ accA[m] = MFMA16(aq[m], b2, fz); accA[m] = MFMA16(aq[m], b1, accA[m]); }
    }
#pragma unroll
    for (int m=0;m<4;++m)
#pragma unroll
      for (int r=0;r<4;++r) rmax[m][r] = fmaxf(rmax[m][r], accB[m][r]);
  }
  {
    s16x8 b1 = *(const s16x8*)(khs + (KK-1)*256 + boff);
    s16x8 b2 = *(const s16x8*)(kls + (KK-1)*256 + boff);
#pragma unroll
    for (int m=0;m<4;++m){ accB[m] = MFMA16(aq[m], b2, fz); accB[m] = MFMA16(aq[m], b1, accB[m]); }
  }
#pragma unroll
  for (int m=0;m<4;++m)
#pragma unroll
    for (int r=0;r<4;++r) rmax[m][r] = fmaxf(fmaxf(rmax[m][r], accA[m][r]), accB[m][r]);
#pragma unroll
  for (int m=0;m<4;++m){
#pragma unroll
    for (int r=0;r<4;++r){
      float v = rmax[m][r];
      v = fmaxf(v, __shfl_xor(v, 1));
      v = fmaxf(v, __shfl_xor(v, 2));
      v = fmaxf(v, __shfl_xor(v, 4));
      v = fmaxf(v, __shfl_xor(v, 8));
      rmax[m][r] = v;
    }
  }
  if (lc == 0){
    const int q4 = l>>4;
#pragma unroll
    for (int m=0;m<4;++m){
#pragma unroll
      for (int r=0;r<4;++r){
        const int row = qt*256 + w*64 + m*16 + q4*4 + r;
        mpart[((long)ks*NBH + bh)*L + row] = rmax[m][r];
      }
    }
  }
}

// ---------------- K3: partial column sums of exp2(s')*w_q — mreduce fused into staging ----------------
// grid (16 kt, 16 bh, 8 qs), block 256 = 4 waves. Stage Q-slice + compute w from mpart, 1 barrier,
// then 2-stage pipelined loop: MFMA for btile k+1 issued before exp/fmac of btile k.
__global__ __launch_bounds__(256) void colexp_k(
    const unsigned short* __restrict__ Kh, const unsigned short* __restrict__ Kl,
    const unsigned short* __restrict__ Qh, const unsigned short* __restrict__ Ql,
    const float* __restrict__ mpart, float* __restrict__ cspart)
{
  const int bh = blockIdx.y, kt = blockIdx.x, qs = blockIdx.z;
  const int t = threadIdx.x, w = t>>6, l = t&63;
  const int half = (l>>4)&1, part = l>>5, lc = l&15;
  __shared__ __align__(16) unsigned short qhs[SLICE*HD];   // 16KB
  __shared__ __align__(16) unsigned short qls[SLICE*HD];   // 16KB
  __shared__ float ws_s[SLICE];                            // 2KB
  {
    const uint4* gh = (const uint4*)(Qh + ((long)bh*L + qs*SLICE)*HD);
    const uint4* gl = (const uint4*)(Ql + ((long)bh*L + qs*SLICE)*HD);
    uint4* sh = (uint4*)qhs; uint4* sl = (uint4*)qls;
#pragma unroll
    for (int i=0;i<4;++i){ sh[t + i*256] = gh[t + i*256]; sl[t + i*256] = gl[t + i*256]; }
    // fused mreduce: w_q = exp2(-max_p mpart[p][bh][q])
#pragma unroll
    for (int rr=0; rr<2; ++rr){
      const int tq = t + rr*256;
      const long qi = (long)bh*L + qs*SLICE + tq;
      float m = -3.4e38f;
#pragma unroll
      for (int p=0;p<NSPLIT;++p) m = fmaxf(m, mpart[(long)p*NBH*L + qi]);
      ws_s[tq] = fast_exp2(-m);
    }
  }
  s16x8 ak[4];
  {
    const unsigned short* Ksrc = part ? Kl : Kh;
#pragma unroll
    for (int m=0;m<4;++m){
      const int key = kt*256 + w*64 + m*16 + lc;
      ak[m] = *(const s16x8*)(Ksrc + (((long)bh*L + key)*HD) + half*8);
    }
  }
  __syncthreads();
  f32x4 fz; fz[0]=0.f; fz[1]=0.f; fz[2]=0.f; fz[3]=0.f;
  f32x4 csum[4];
#pragma unroll
  for (int m=0;m<4;++m){ csum[m][0]=0.f; csum[m][1]=0.f; csum[m][2]=0.f; csum[m][3]=0.f; }
  const int boff = lc*HD + half*8;
  f32x4 accA[4], accB[4];
  {
    s16x8 b1 = *(const s16x8*)(qhs + boff);
    s16x8 b2 = *(const s16x8*)(qls + boff);
#pragma unroll
    for (int m=0;m<4;++m){ accA[m] = MFMA16(ak[m], b2, fz); accA[m] = MFMA16(ak[m], b1, accA[m]); }
  }
  for (int kk=0; kk<KK-2; kk+=2){
    {
      s16x8 b1 = *(const s16x8*)(qhs + (kk+1)*256 + boff);
      s16x8 b2 = *(const s16x8*)(qls + (kk+1)*256 + boff);
#pragma unroll
      for (int m=0;m<4;++m){ accB[m] = MFMA16(ak[m], b2, fz); accB[m] = MFMA16(ak[m], b1, accB[m]); }
    }
    {
      const float cw = ws_s[kk*16 + lc];
#pragma unroll
      for (int m=0;m<4;++m)
#pragma unroll
        for (int r=0;r<4;++r)
          csum[m][r] = fmaf(fast_exp2(accA[m][r]), cw, csum[m][r]);
    }
    {
      s16x8 b1 = *(const s16x8*)(qhs + (kk+2)*256 + boff);
      s16x8 b2 = *(const s16x8*)(qls + (kk+2)*256 + boff);
#pragma unroll
      for (int m=0;m<4;++m){ accA[m] = MFMA16(ak[m], b2, fz); accA[m] = MFMA16(ak[m], b1, accA[m]); }
    }
    {
      const float cw = ws_s[(kk+1)*16 + lc];
#pragma unroll
      for (int m=0;m<4;++m)
#pragma unroll
        for (int r=0;r<4;++r)
          csum[m][r] = fmaf(fast_exp2(accB[m][r]), cw, csum[m][r]);
    }
  }
  {
    s16x8 b1 = *(const s16x8*)(qhs + (KK-1)*256 + boff);
    s16x8 b2 = *(const s16x8*)(qls + (KK-1)*256 + boff);
#pragma unroll
    for (int m=0;m<4;++m){ accB[m] = MFMA16(ak[m], b2, fz); accB[m] = MFMA16(ak[m], b1, accB[m]); }
  }
  {
    const float cwA = ws_s[(KK-2)*16 + lc];
    const float cwB = ws_s[(KK-1)*16 + lc];
#pragma unroll
    for (int m=0;m<4;++m)
#pragma unroll
      for (int r=0;r<4;++r){
        csum[m][r] = fmaf(fast_exp2(accA[m][r]), cwA, csum[m][r]);
        csum[m][r] = fmaf(fast_exp2(accB[m][r]), cwB, csum[m][r]);
      }
  }
#pragma unroll
  for (int m=0;m<4;++m){
#pragma unroll
    for (int r=0;r<4;++r){
      float v = csum[m][r];
      v += __shfl_xor(v, 1);
      v += __shfl_xor(v, 2);
      v += __shfl_xor(v, 4);
      v += __shfl_xor(v, 8);
      csum[m][r] = v;
    }
  }
  if (lc == 0){
    const int k4 = l>>4;
#pragma unroll
    for (int m=0;m<4;++m){
#pragma unroll
      for (int r=0;r<4;++r){
        const int key = kt*256 + w*64 + m*16 + k4*4 + r;
        cspart[((long)qs*NBH + bh)*L + key] = csum[m][r];
      }
    }
  }
}

// ---------------- K4: exact 3-level radix-select top-41 + gather Ks/Vs (csreduce fused) ----------------
__global__ __launch_bounds__(256) void topk_gather(
    const float* __restrict__ cspart,
    const unsigned short* __restrict__ Kh, const unsigned short* __restrict__ Kl,
    const float* __restrict__ V,
    float* __restrict__ Ks, float* __restrict__ Vs)
{
  const int bh = blockIdx.x;
  const int t = threadIdx.x;
  __shared__ float vals[4096];
  __shared__ unsigned hist[2048];
  __shared__ unsigned suf[256];
  __shared__ int meta[4];           // 0:B 1:nab 2:ngt 3:ntie
  __shared__ int sel[SK];
  __shared__ int sorted[SK];
  __shared__ int tiei[4096];

  for (int i=t; i<1024; i+=256){
    float4 s = {0.f,0.f,0.f,0.f};
#pragma unroll
    for (int p=0;p<NSPLIT;++p){
      float4 v = *(const float4*)(cspart + ((long)p*NBH + bh)*L + i*4);
      s.x += v.x; s.y += v.y; s.z += v.z; s.w += v.w;
    }
    *(float4*)&vals[i*4] = s;
  }
  __syncthreads();

  int target = SK;
  unsigned B1 = 0, P2 = 0, T = 0;
#pragma unroll
  for (int pass=0; pass<3; ++pass){
    const int nb = (pass<2) ? 2048 : 1024;
    const int chunk = nb >> 8;
    for (int i=t;i<nb;i+=256) hist[i]=0u;
    __syncthreads();
    for (int i=t;i<4096;i+=256){
      const unsigned u = __float_as_uint(vals[i]);
      bool ok; int bk;
      if (pass==0){ ok = true;              bk = (int)(u>>21); }
      else if (pass==1){ ok = ((u>>21)==B1); bk = (int)((u>>10)&0x7FFu); }
      else { ok = ((u>>10)==P2);            bk = (int)(u&0x3FFu); }
      if (ok) atomicAdd(&hist[bk], 1u);
    }
    __syncthreads();
    {
      unsigned c=0;
#pragma unroll
      for (int b=0;b<8;++b) if (b<chunk) c += hist[t*chunk+b];
      suf[t]=c;
    }
    __syncthreads();
    for (int off=1; off<256; off<<=1){
      unsigned add = (t+off<256)? suf[t+off] : 0u;
      __syncthreads();
      suf[t] += add;
      __syncthreads();
    }
    {
      const unsigned mysuf = suf[t];
      const unsigned nxt = (t==255)?0u:suf[t+1];
      if (mysuf >= (unsigned)target && nxt < (unsigned)target){
        unsigned running = nxt;
        for (int b=t*chunk+chunk-1; b>=t*chunk; --b){
          const unsigned h = hist[b];
          if (running + h >= (unsigned)target){ meta[0]=b; meta[1]=(int)running; break; }
          running += h;
        }
      }
    }
    __syncthreads();
    const unsigned B = (unsigned)meta[0];
    target -= meta[1];
    if (pass==0) B1 = B;
    else if (pass==1) P2 = (B1<<11)|B;
    else T = (P2<<10)|B;
    __syncthreads();
  }
  if (t==0){ meta[2]=0; meta[3]=0; }
  __syncthreads();
  for (int i=t;i<4096;i+=256){
    const unsigned u = __float_as_uint(vals[i]);
    if (u > T){ int p = atomicAdd(&meta[2],1); sel[p]=i; }
    else if (u == T){ int p = atomicAdd(&meta[3],1); tiei[p]=i; }
  }
  __syncthreads();
  const int ngt = meta[2];
  const int ntie = meta[3];
  for (int j=t; j<ntie; j+=256){
    const int x = tiei[j];
    int rk=0;
    for (int k=0;k<ntie;++k) rk += (tiei[k] < x);
    if (rk < target) sel[ngt+rk] = x;
  }
  __syncthreads();
  if (t<SK){
    int x=sel[t]; int rk=0;
    for (int j=0;j<SK;++j) rk += (sel[j]<x);
    sorted[rk]=x;
  }
  __syncthreads();
  for (int i=t;i<SK*HD;i+=256){
    const int j=i>>4, dd=i&15;
    const int key=sorted[j];
    const long src=((long)bh*L+key)*HD+dd;
    Ks[(long)bh*SK*HD+i]=bf2f(Kh[src])+bf2f(Kl[src]);
    Vs[(long)bh*SK*HD+i]=V[src];
  }
}

// ---------------- K5: sampled attention — lane-pair split, 2-pass register softmax ----------------
__global__ __launch_bounds__(256) void sattn(
    const unsigned short* __restrict__ Qh, const unsigned short* __restrict__ Ql,
    const float* __restrict__ Ks, const float* __restrict__ Vs,
    unsigned short* __restrict__ AOh, unsigned short* __restrict__ AOl)
{
  const int bh = blockIdx.y, qb = blockIdx.x;
  const int t = threadIdx.x;
  __shared__ float ks[SK*HD], vs[SK*HD];
  for (int i=t; i<SK*HD; i+=256){
    ks[i] = Ks[(long)bh*SK*HD + i];
    vs[i] = Vs[(long)bh*SK*HD + i];
  }
  __syncthreads();
  const int q = qb*128 + (t>>1);
  const int half = t&1;
  const long qo = ((long)bh*L + q)*HD;
  float qv[16];
  {
    s16x8 h0 = *(const s16x8*)(Qh+qo);
    s16x8 h1 = *(const s16x8*)(Qh+qo+8);
    s16x8 l0 = *(const s16x8*)(Ql+qo);
    s16x8 l1 = *(const s16x8*)(Ql+qo+8);
#pragma unroll
    for (int d=0; d<8; ++d){
      qv[d]   = bf2f((unsigned short)h0[d]) + bf2f((unsigned short)l0[d]);
      qv[d+8] = bf2f((unsigned short)h1[d]) + bf2f((unsigned short)l1[d]);
    }
  }
  // pass 1: all scores into registers
  float sc[21];
#pragma unroll
  for (int i=0;i<21;++i){
    const int j = half + 2*i;
    if (j < SK){
      float4 k0 = *(const float4*)&ks[j*HD+0];
      float4 k1 = *(const float4*)&ks[j*HD+4];
      float4 k2 = *(const float4*)&ks[j*HD+8];
      float4 k3 = *(const float4*)&ks[j*HD+12];
      float s = qv[0]*k0.x;
      s = fmaf(qv[1],k0.y,s); s = fmaf(qv[2],k0.z,s); s = fmaf(qv[3],k0.w,s);
      s = fmaf(qv[4],k1.x,s); s = fmaf(qv[5],k1.y,s); s = fmaf(qv[6],k1.z,s); s = fmaf(qv[7],k1.w,s);
      s = fmaf(qv[8],k2.x,s); s = fmaf(qv[9],k2.y,s); s = fmaf(qv[10],k2.z,s); s = fmaf(qv[11],k2.w,s);
      s = fmaf(qv[12],k3.x,s); s = fmaf(qv[13],k3.y,s); s = fmaf(qv[14],k3.z,s); s = fmaf(qv[15],k3.w,s);
      sc[i] = s;
    } else {
      sc[i] = -3.4e38f;
    }
  }
  // max
  float m = sc[0];
#pragma unroll
  for (int i=1;i<21;++i) m = fmaxf(m, sc[i]);
  // pass 2: exp + weighted V accumulate (invalid keys give p=0)
  float lrun = 0.f, out[16];
#pragma unroll
  for (int d=0; d<16; ++d) out[d] = 0.f;
#pragma unroll
  for (int i=0;i<21;++i){
    const int j = half + 2*i;
    const float p = fast_exp2(sc[i] - m);
    lrun += p;
    if (j < SK){
      float4 v0 = *(const float4*)&vs[j*HD+0];
      float4 v1 = *(const float4*)&vs[j*HD+4];
      float4 v2 = *(const float4*)&vs[j*HD+8];
      float4 v3 = *(const float4*)&vs[j*HD+12];
      out[0]=fmaf(p,v0.x,out[0]); out[1]=fmaf(p,v0.y,out[1]); out[2]=fmaf(p,v0.z,out[2]); out[3]=fmaf(p,v0.w,out[3]);
      out[4]=fmaf(p,v1.x,out[4]); out[5]=fmaf(p,v1.y,out[5]); out[6]=fmaf(p,v1.z,out[6]); out[7]=fmaf(p,v1.w,out[7]);
      out[8]=fmaf(p,v2.x,out[8]); out[9]=fmaf(p,v2.y,out[9]); out[10]=fmaf(p,v2.z,out[10]); out[11]=fmaf(p,v2.w,out[11]);
      out[12]=fmaf(p,v3.x,out[12]); out[13]=fmaf(p,v3.y,out[13]); out[14]=fmaf(p,v3.z,out[14]); out[15]=fmaf(p,v3.w,out[15]);
    }
  }
  // merge lane-pair softmax states
  const float mo = __shfl_xor(m, 1);
  const float lo = __shfl_xor(lrun, 1);
  const float mm = fmaxf(m, mo);
  const float cs_ = fast_exp2(m - mm);
  const float co_ = fast_exp2(mo - mm);
  const float ltot = fmaf(lrun, cs_, lo*co_);
  const float inv = 1.f / ltot;
#pragma unroll
  for (int d=0; d<16; ++d){
    const float ov = __shfl_xor(out[d], 1);
    out[d] = fmaf(out[d]*cs_, inv, ov*co_*inv);
  }
  if (half == 0){
    const int b = bh>>3, h = bh&7;
    const long row = (long)b*L + q;
    unsigned short hv[16], lv[16];
#pragma unroll
    for (int d=0; d<16; ++d){
      const float v = out[d];
      hv[d] = f2bf(v);
      lv[d] = f2bf(v - bf2f(hv[d]));
    }
    unsigned short* oh = AOh + row*DM + h*HD;
    unsigned short* ol = AOl + row*DM + h*HD;
    *(uint4*)(oh)   = *(uint4*)(hv);
    *(uint4*)(oh+8) = *(uint4*)(hv+8);
    *(uint4*)(ol)   = *(uint4*)(lv);
    *(uint4*)(ol+8) = *(uint4*)(lv+8);
  }
}

// ---------------- K6: MFMA output projection ----------------
// grid 128, block 256 (4 waves). Wave: 16 rows x 128 cols.
__global__ __launch_bounds__(256) void outproj_mfma(
    const unsigned short* __restrict__ AOh, const unsigned short* __restrict__ AOl,
    const unsigned short* __restrict__ Wph, const unsigned short* __restrict__ Wpl,
    const float* __restrict__ bo, float* __restrict__ out)
{
  __shared__ __align__(16) unsigned short wh[16384];
  __shared__ __align__(16) unsigned short wl[16384];
  const int t = threadIdx.x;
  {
    const uint4* gh = (const uint4*)(Wph + (long)3*16384);
    const uint4* gl = (const uint4*)(Wpl + (long)3*16384);
    uint4* sh = (uint4*)wh; uint4* sl = (uint4*)wl;
#pragma unroll
    for (int i=0;i<8;++i){ sh[t + i*256] = gh[t + i*256]; sl[t + i*256] = gl[t + i*256]; }
  }
  __syncthreads();
  const int w = t>>6, l = t&63;
  const int lc = l&15, g = l>>4;
  const int mbase = blockIdx.x*64 + w*16;
  f32x4 acc[8];
#pragma unroll
  for (int nt=0;nt<8;++nt){ acc[nt][0]=0.f; acc[nt][1]=0.f; acc[nt][2]=0.f; acc[nt][3]=0.f; }
  const unsigned short* __restrict__ Asrc = (g<2)? AOh : AOl;
  const int koff = (g&1)*8;
  for (int kc=0; kc<8; ++kc){
    s16x8 a = *(const s16x8*)(Asrc + ((long)(mbase + lc))*128 + kc*16 + koff);
#pragma unroll
    for (int nt=0;nt<8;++nt){
      const int fi = (kc*2+(g&1))*128 + nt*16 + lc;
      s16x8 b1 = ((const s16x8*)wh)[fi];
      s16x8 b2 = ((const s16x8*)wl)[fi];
      acc[nt] = MFMA16(a, b1, acc[nt]);
      acc[nt] = MFMA16(a, b2, acc[nt]);
    }
  }
#pragma unroll
  for (int nt=0;nt<8;++nt){
    const float bb = bo[nt*16 + lc];
#pragma unroll
    for (int r=0;r<4;++r){
      const int row = mbase + g*4 + r;
      out[(long)row*DM + nt*16 + lc] = acc[nt][r] + bb;
    }
  }
}

extern "C" void kernel_launch(void* const* d_in, const int* in_sizes, int n_in,
                              void* d_out, int out_size, void* d_ws, size_t ws_size,
                              hipStream_t stream)
{
  const float* x  = (const float*)d_in[0];
  const float* Wq = (const float*)d_in[1];
  const float* bq = (const float*)d_in[2];
  const float* Wk = (const float*)d_in[3];
  const float* bk = (const float*)d_in[4];
  const float* Wv = (const float*)d_in[5];
  const float* bv = (const float*)d_in[6];
  const float* Wo = (const float*)d_in[7];
  const float* bo = (const float*)d_in[8];
  float* out = (float*)d_out;

  char* wsp = (char*)d_ws;
  size_t o = 0;
  auto alloc = [&](size_t bytes)->char*{
    char* p = wsp + o; o += (bytes + 255) & ~(size_t)255; return p;
  };
  unsigned short* Qh = (unsigned short*)alloc((size_t)NBH*L*HD*2);
  unsigned short* Ql = (unsigned short*)alloc((size_t)NBH*L*HD*2);
  unsigned short* Kh = (unsigned short*)alloc((size_t)NBH*L*HD*2);
  unsigned short* Kl = (unsigned short*)alloc((size_t)NBH*L*HD*2);
  float* Vv    = (float*)alloc((size_t)NBH*L*HD*4);
  float* mpart = (float*)alloc((size_t)NSPLIT*NBH*L*4);
  float* cspart= (float*)alloc((size_t)NSPLIT*NBH*L*4);
  float* Ks    = (float*)alloc((size_t)NBH*SK*HD*4);
  float* Vs    = (float*)alloc((size_t)NBH*SK*HD*4);
  unsigned short* Xh  = (unsigned short*)alloc((size_t)2*L*DM*2);
  unsigned short* Xl  = (unsigned short*)alloc((size_t)2*L*DM*2);
  unsigned short* AOh = (unsigned short*)alloc((size_t)2*L*DM*2);
  unsigned short* AOl = (unsigned short*)alloc((size_t)2*L*DM*2);
  unsigned short* Wph = (unsigned short*)alloc((size_t)4*16384*2);
  unsigned short* Wpl = (unsigned short*)alloc((size_t)4*16384*2);

  prep<<<1280,256,0,stream>>>(x,Wq,Wk,Wv,Wo,Xh,Xl,Wph,Wpl);
  proj_mfma<<<dim3(128,3),256,0,stream>>>(Xh,Xl,Wph,Wpl,bq,bk,bv,Qh,Ql,Kh,Kl,Vv);
  rowmax_k<<<dim3(16,16,NSPLIT),256,0,stream>>>(Qh,Ql,Kh,Kl,mpart);
  colexp_k<<<dim3(16,16,NSPLIT),256,0,stream>>>(Kh,Kl,Qh,Ql,mpart,cspart);
  topk_gather<<<16,256,0,stream>>>(cspart,Kh,Kl,Vv,Ks,Vs);
  sattn<<<dim3(32,16),256,0,stream>>>(Qh,Ql,Ks,Vs,AOh,AOl);
  outproj_mfma<<<128,256,0,stream>>>(AOh,AOl,Wph,Wpl,bo,out);
}